// Round 1
// baseline (193.380 us; speedup 1.0000x reference)
//
#include <hip/hip_runtime.h>

#define N_NODES 50000
#define N_EDGES 800000
#define D 128

// ---------------- K0: u = W @ ka[0:128], v = W @ ka[128:256] ----------------
__global__ void k0_uv(const float* __restrict__ W, const float* __restrict__ ka,
                      float* __restrict__ u, float* __restrict__ v) {
    int t = threadIdx.x;            // 256 threads
    int k = t & 127;
    const float* w = ka + ((t >> 7) ? 128 : 0);
    float s = 0.f;
    for (int j = 0; j < D; ++j) s += W[k * D + j] * w[j];
    if (t < 128) u[k] = s; else v[k] = s;
}

// ---------------- K1: row_ptr[n] = lower_bound(src, n) ----------------------
__global__ void k1_rowptr(const int* __restrict__ edges, int* __restrict__ row_ptr,
                          int n_nodes, int n_edges) {
    int n = blockIdx.x * blockDim.x + threadIdx.x;
    if (n > n_nodes) return;
    int lo = 0, hi = n_edges;
    while (lo < hi) {
        int mid = (lo + hi) >> 1;
        if (edges[2 * mid] < n) lo = mid + 1; else hi = mid;
    }
    row_ptr[n] = lo;
}

// ---------------- K2: a_src[n] = X[n].u ; a_dst[n] = X[n].v  (wave/row) -----
__global__ __launch_bounds__(256) void k2_proj(const float* __restrict__ X,
                                               const float* __restrict__ u,
                                               const float* __restrict__ v,
                                               float* __restrict__ a_src,
                                               float* __restrict__ a_dst,
                                               int n_nodes) {
    int gid  = blockIdx.x * blockDim.x + threadIdx.x;
    int node = gid >> 6;            // one 64-lane wave per node
    int lane = gid & 63;
    if (node >= n_nodes) return;
    const float2* x2 = (const float2*)(X + (long)node * D);
    float2 a  = x2[lane];
    float2 uu = ((const float2*)u)[lane];
    float2 vv = ((const float2*)v)[lane];
    float ps = a.x * uu.x + a.y * uu.y;
    float pd = a.x * vv.x + a.y * vv.y;
    for (int off = 32; off > 0; off >>= 1) {
        ps += __shfl_down(ps, off);
        pd += __shfl_down(pd, off);
    }
    if (lane == 0) { a_src[node] = ps; a_dst[node] = pd; }
}

// ---------------- K3: per-node segment gather/aggregate ---------------------
// agg[n][c] = (sum_e s_e * X[dst_e][c]) / (sum_e s_e), written to d_out.
#define SEG_CHUNK 512
__global__ __launch_bounds__(128) void k3_gather(const int* __restrict__ edges,
                                                 const int* __restrict__ row_ptr,
                                                 const float* __restrict__ a_src,
                                                 const float* __restrict__ a_dst,
                                                 const float* __restrict__ X,
                                                 float* __restrict__ agg) {
    __shared__ float ss[SEG_CHUNK];
    __shared__ int   sd[SEG_CHUNK];
    int n = blockIdx.x;
    int tid = threadIdx.x;
    int start = row_ptr[n], end = row_ptr[n + 1];
    float asn = a_src[n];
    float acc = 0.f, denom = 0.f;
    for (int base = start; base < end; base += SEG_CHUNK) {
        int cnt = min(SEG_CHUNK, end - base);
        for (int i = tid; i < cnt; i += 128) {
            int d = edges[2 * (base + i) + 1];
            float lg = asn + a_dst[d];
            lg = (lg >= 0.f) ? lg : 0.2f * lg;     // leaky_relu(0.2)
            lg = fminf(fmaxf(lg, -2.f), 2.f);      // clip
            ss[i] = __expf(lg);
            sd[i] = d;
        }
        __syncthreads();
        for (int j = 0; j < cnt; ++j) {
            float s = ss[j];
            int   d = sd[j];
            denom += s;
            acc   += s * X[(long)d * D + tid];     // coalesced 512B row read
        }
        __syncthreads();
    }
    agg[(long)n * D + tid] = (end > start) ? (acc / denom) : 0.f;
}

// ---------------- K4: out = agg @ W, in-place on d_out ----------------------
#define K4_ROWS 32
__global__ __launch_bounds__(256) void k4_gemm(float* __restrict__ out,
                                               const float* __restrict__ W,
                                               int n_rows) {
    __shared__ float Ws[D * D];        // 64 KB
    __shared__ float As[K4_ROWS * D];  // 16 KB
    int tid = threadIdx.x;
    // stage W (row-major)
    {
        const float4* W4 = (const float4*)W;
        float4* Ws4 = (float4*)Ws;
        for (int i = tid; i < D * D / 4; i += 256) Ws4[i] = W4[i];
    }
    int row0 = blockIdx.x * K4_ROWS;
    // stage A tile (current d_out rows) before overwriting
    {
        float4* As4 = (float4*)As;
        for (int i = tid; i < K4_ROWS * D / 4; i += 256) {
            int r = row0 + i / (D / 4);
            float4 val = make_float4(0.f, 0.f, 0.f, 0.f);
            if (r < n_rows) val = ((const float4*)out)[(long)r * (D / 4) + (i % (D / 4))];
            As4[i] = val;
        }
    }
    __syncthreads();

    int cg = tid & 31;     // 32 col-groups of 4 cols
    int rg = tid >> 5;     // 8 row-groups of 4 rows
    int c0 = cg * 4;
    float4 acc[4];
    for (int i = 0; i < 4; ++i) acc[i] = make_float4(0.f, 0.f, 0.f, 0.f);

    for (int k = 0; k < D; k += 4) {
        float4 w0 = *(const float4*)&Ws[(k + 0) * D + c0];
        float4 w1 = *(const float4*)&Ws[(k + 1) * D + c0];
        float4 w2 = *(const float4*)&Ws[(k + 2) * D + c0];
        float4 w3 = *(const float4*)&Ws[(k + 3) * D + c0];
#pragma unroll
        for (int i = 0; i < 4; ++i) {
            float4 a4 = *(const float4*)&As[(rg * 4 + i) * D + k];
            acc[i].x += a4.x * w0.x; acc[i].y += a4.x * w0.y; acc[i].z += a4.x * w0.z; acc[i].w += a4.x * w0.w;
            acc[i].x += a4.y * w1.x; acc[i].y += a4.y * w1.y; acc[i].z += a4.y * w1.z; acc[i].w += a4.y * w1.w;
            acc[i].x += a4.z * w2.x; acc[i].y += a4.z * w2.y; acc[i].z += a4.z * w2.z; acc[i].w += a4.z * w2.w;
            acc[i].x += a4.w * w3.x; acc[i].y += a4.w * w3.y; acc[i].z += a4.w * w3.z; acc[i].w += a4.w * w3.w;
        }
    }
#pragma unroll
    for (int i = 0; i < 4; ++i) {
        int r = row0 + rg * 4 + i;
        if (r < n_rows) *(float4*)&out[(long)r * D + c0] = acc[i];
    }
}

extern "C" void kernel_launch(void* const* d_in, const int* in_sizes, int n_in,
                              void* d_out, int out_size, void* d_ws, size_t ws_size,
                              hipStream_t stream) {
    const float* X     = (const float*)d_in[0];   // 50000 x 128
    const int*   edges = (const int*)d_in[1];     // 800000 x 2 (src,dst), src sorted
    const float* W     = (const float*)d_in[2];   // 128 x 128
    const float* ka    = (const float*)d_in[3];   // 256 x 1

    // workspace layout (bytes)
    char* ws = (char*)d_ws;
    int*   row_ptr = (int*)ws;                       // 50001 ints (pad to 50004)
    float* a_src   = (float*)(ws + 50004 * 4);       // 50000 floats
    float* a_dst   = a_src + N_NODES;                // 50000 floats
    float* u       = a_dst + N_NODES;                // 128
    float* v       = u + D;                          // 128

    float* out = (float*)d_out;                      // also holds agg between K3 and K4

    k0_uv<<<1, 256, 0, stream>>>(W, ka, u, v);
    k1_rowptr<<<(N_NODES + 1 + 255) / 256, 256, 0, stream>>>(edges, row_ptr, N_NODES, N_EDGES);
    k2_proj<<<(N_NODES * 64 + 255) / 256, 256, 0, stream>>>(X, u, v, a_src, a_dst, N_NODES);
    k3_gather<<<N_NODES, 128, 0, stream>>>(edges, row_ptr, a_src, a_dst, X, out);
    k4_gemm<<<(N_NODES + K4_ROWS - 1) / K4_ROWS, 256, 0, stream>>>(out, W, N_NODES);
}